// Round 10
// baseline (348.417 us; speedup 1.0000x reference)
//
#include <hip/hip_runtime.h>
#include <hip/hip_bf16.h>
#include <math.h>
#include <string.h>

typedef __attribute__((ext_vector_type(8))) short bf16x8;
typedef __attribute__((ext_vector_type(4))) float f32x4;
typedef __attribute__((ext_vector_type(4))) unsigned short u16x4;

constexpr int Bn = 64;    // dialogues
constexpr int Ln = 512;   // utterances
constexpr int Hd = 768;   // hidden
constexpr int Nn = 50;    // nodes per dialogue
constexpr int On = 768;   // output dim
constexpr int RP = 64;    // padded rows per dialogue (M = Bn*RP = 4096)

constexpr int AUXW = 5 * Bn * RP + 3 * Bn;  // accumulators + 3x64 tickets

__device__ __forceinline__ f32x4 MFMA(bf16x8 a, bf16x8 b, f32x4 c) {
  return __builtin_amdgcn_mfma_f32_16x16x32_bf16(a, b, c, 0, 0, 0);
}
__device__ __forceinline__ unsigned short f2bb(float v) {
  __hip_bfloat16 h = __float2bfloat16(v);
  return *(unsigned short*)&h;
}
// Async global->LDS, 16B per lane. LDS dest = wave-uniform base + lane*16.
__device__ __forceinline__ void gload16(const void* g, void* l) {
  __builtin_amdgcn_global_load_lds(
      (const __attribute__((address_space(1))) void*)g,
      (__attribute__((address_space(3))) void*)l, 16, 0, 0);
}

// ===========================================================================
// prep, one launch, job ranges by blockIdx.x:
//   [0,2304)      transpose+cvt W1,W2,Wa,Wl (f32 -> bf16^T)
//   [2304,6400)   gather+PE into padded xb (bf16) / xres (f32); pad rows = 0
//   [6400,6481)   zero aux accumulators + ticket counters
struct PrepArgs {
  const float* src[4];
  __hip_bfloat16* dst[4];
  const float* emb;
  const int* ids;
  float* xres;
  __hip_bfloat16* xb;
  float* aux;
};

__global__ __launch_bounds__(256) void prep_kernel(PrepArgs a) {
  int bx = blockIdx.x;
  if (bx < 2304) {
    __shared__ float tile[32][33];
    int job = bx / 576, t = bx % 576;
    const float* W = a.src[job];
    __hip_bfloat16* Wt = a.dst[job];
    int tx = (t % 24) * 32, ty = (t / 24) * 32;
    int c = threadIdx.x & 31, r0 = threadIdx.x >> 5;
    for (int r = r0; r < 32; r += 8)
      tile[r][c] = W[(size_t)(tx + r) * Hd + ty + c];
    __syncthreads();
    for (int r = r0; r < 32; r += 8)
      Wt[(size_t)(ty + r) * Hd + tx + c] = __float2bfloat16(tile[c][r]);
  } else if (bx < 6400) {
    int bn = bx - 2304;          // b*RP + i
    int b = bn >> 6, i = bn & 63;
    __hip_bfloat16* xbo = a.xb + (size_t)bn * Hd;
    float* xro = a.xres + (size_t)bn * Hd;
    if (i < Nn) {
      int id = a.ids[b * Nn + i];
      const float* src = a.emb + ((size_t)b * Ln + id) * Hd;
      const float kLog = 9.210340371976184f / (float)Hd;  // ln(10000)/H
      for (int h = threadIdx.x; h < Hd; h += 256) {
        float freq = expf(-(float)(h & ~1) * kLog);
        float ang = (float)i * freq;
        float v = src[h] + ((h & 1) ? cosf(ang) : sinf(ang));
        xbo[h] = __float2bfloat16(v);
        xro[h] = v;
      }
    } else {
      for (int h = threadIdx.x; h < Hd; h += 256) {
        xbo[h] = __float2bfloat16(0.f);
        xro[h] = 0.f;
      }
    }
  } else {
    int idx = (bx - 6400) * 256 + threadIdx.x;
    if (idx < AUXW) a.aux[idx] = 0.f;
  }
}

// ===========================================================================
// Fused GEMM + ticketed per-dialogue epilogue stage.
// grid = (Bn, 12), block 512 (8 waves). GEMM body = R8's proven kernel
// (gload_lds + XOR-swizzle, wave owns 16x32 sub-tile).
// After the epilogue each block bumps tick[b]; the block drawing old==11
// runs POST for dialogue b inline (no polling -> no deadlock possible):
//   POST 1/2: attention apply (softmax ONCE per dialogue, was 12x) -> hb/hf
//   POST 3  : pool softmax + weighted sum + final linear -> out
// Cross-XCD visibility: WhT stored via agent-scope relaxed atomic stores
// (device-coherent, no wbL2 fences); ssrc/sdst/sraw are device atomics;
// taker issues ONE acquire fence (64 per kernel). Math orders unchanged.
struct GArgs {
  const __hip_bfloat16 *A, *Bt;
  const float *bias, *avec;
  __hip_bfloat16* WhT;
  float *o1, *o2;
  const int* adj;
  const float* ab;
  const float* xres;
  float* hf;
  __hip_bfloat16* hb;
  const float* h2;             // h2f (pool)
  const __hip_bfloat16* Wlt;   // pool
  const float* bl;             // pool
  float* out;                  // pool
  int* tick;
};

template <int EPI, int POST>
__global__ __launch_bounds__(512) void gfuse_kernel(GArgs g) {
  __shared__ __align__(16) char arena[33024];
  int tid = threadIdx.x;
  int wave = tid >> 6, lane = tid & 63;
  int lr = lane & 15, lq = lane >> 4;
  int wr = wave >> 1, wc = wave & 1;
  int b = blockIdx.x, col0 = blockIdx.y * 64;
  int row0 = b * RP;

  {  // ---------------- GEMM phase (R8 body) ----------------
    char* AsB = arena;
    char* BsB = arena + 16384;
    int srow = wave * 8 + (lane >> 3);
    int swz = ((lane & 7) ^ (lane >> 3)) * 8;
    const __hip_bfloat16* Ap = g.A + (size_t)(row0 + srow) * Hd + swz;
    const __hip_bfloat16* Bp = g.Bt + (size_t)(col0 + srow) * Hd + swz;
    int ldsw = wave * 1024;
    auto stage = [&](int buf, int kt) {
      gload16(Ap + kt, AsB + buf * 8192 + ldsw);
      gload16(Bp + kt, BsB + buf * 8192 + ldsw);
    };
    f32x4 acc[2] = {};
    stage(0, 0);
    __syncthreads();
    int cur = 0;
    int arow = wr * 16 + lr;
    int s7 = lr & 7;
    int c0 = (lq ^ s7) * 16;
    int c1 = ((4 + lq) ^ s7) * 16;
    for (int kt = 64; kt < Hd; kt += 64) {
      stage(cur ^ 1, kt);
      const char* Ab = AsB + cur * 8192 + arow * 128;
      bf16x8 af0 = *(const bf16x8*)(Ab + c0);
      bf16x8 af1 = *(const bf16x8*)(Ab + c1);
#pragma unroll
      for (int ct = 0; ct < 2; ++ct) {
        const char* Bb = BsB + cur * 8192 + (wc * 32 + ct * 16 + lr) * 128;
        acc[ct] = MFMA(af0, *(const bf16x8*)(Bb + c0), acc[ct]);
        acc[ct] = MFMA(af1, *(const bf16x8*)(Bb + c1), acc[ct]);
      }
      __syncthreads();
      cur ^= 1;
    }
    {
      const char* Ab = AsB + cur * 8192 + arow * 128;
      bf16x8 af0 = *(const bf16x8*)(Ab + c0);
      bf16x8 af1 = *(const bf16x8*)(Ab + c1);
#pragma unroll
      for (int ct = 0; ct < 2; ++ct) {
        const char* Bb = BsB + cur * 8192 + (wc * 32 + ct * 16 + lr) * 128;
        acc[ct] = MFMA(af0, *(const bf16x8*)(Bb + c0), acc[ct]);
        acc[ct] = MFMA(af1, *(const bf16x8*)(Bb + c1), acc[ct]);
      }
    }
    int lrow0 = wr * 16 + lq * 4;
    if (EPI == 0) {
      float ps[4] = {}, pd[4] = {};
#pragma unroll
      for (int ct = 0; ct < 2; ++ct) {
        int gc = col0 + wc * 32 + ct * 16 + lr;
        float bv = g.bias[gc];
        float a_s = g.avec[gc], a_d = g.avec[Hd + gc];
        u16x4 pk;
#pragma unroll
        for (int r = 0; r < 4; ++r) {
          float v = acc[ct][r] + bv;
          pk[r] = f2bb(v);
          ps[r] += v * a_s;
          pd[r] += v * a_d;
        }
        unsigned long long pv;
        __builtin_memcpy(&pv, &pk, 8);
        __hip_atomic_store(
            (unsigned long long*)(g.WhT + ((size_t)b * Hd + gc) * RP + lrow0),
            pv, __ATOMIC_RELAXED, __HIP_MEMORY_SCOPE_AGENT);
      }
#pragma unroll
      for (int off = 8; off; off >>= 1)
#pragma unroll
        for (int r = 0; r < 4; ++r) {
          ps[r] += __shfl_xor(ps[r], off);
          pd[r] += __shfl_xor(pd[r], off);
        }
      if (lr == 0)
#pragma unroll
        for (int r = 0; r < 4; ++r) {
          int row = lrow0 + r;
          if (row < Nn) {
            atomicAdd(&g.o1[b * RP + row], ps[r]);
            atomicAdd(&g.o2[b * RP + row], pd[r]);
          }
        }
    } else {
      float pr[4] = {};
#pragma unroll
      for (int ct = 0; ct < 2; ++ct) {
        int gc = col0 + wc * 32 + ct * 16 + lr;
        float bv = g.bias[gc];
        float vv_ = g.avec[gc];
#pragma unroll
        for (int r = 0; r < 4; ++r) pr[r] += tanhf(acc[ct][r] + bv) * vv_;
      }
#pragma unroll
      for (int off = 8; off; off >>= 1)
#pragma unroll
        for (int r = 0; r < 4; ++r) pr[r] += __shfl_xor(pr[r], off);
      if (lr == 0)
#pragma unroll
        for (int r = 0; r < 4; ++r) {
          int row = lrow0 + r;
          if (row < Nn) atomicAdd(&g.o1[b * RP + row], pr[r]);
        }
    }
  }

  // ---------------- ticket: last block of dialogue b runs POST ----------
  __syncthreads();  // drains all stores/atomics (vmcnt 0) before ticket
  int* flag = (int*)arena;
  if (tid == 0) {
    int old = __hip_atomic_fetch_add(&g.tick[b], 1, __ATOMIC_ACQ_REL,
                                     __HIP_MEMORY_SCOPE_AGENT);
    *flag = (old == 11) ? 1 : 0;
  }
  __syncthreads();
  bool take = (*flag != 0);
  __syncthreads();  // all read flag before arena reuse
  if (!take) return;
  if (tid == 0) __builtin_amdgcn_fence(__ATOMIC_ACQUIRE, "agent");
  __syncthreads();  // acquire (L1/L2 inv) ordered before all POST loads

  if (POST == 1 || POST == 2) {
    // attention apply for dialogue b, ALL 768 cols, softmax once.
    float* attL = (float*)arena;                                   // Nn*52 f32
    __hip_bfloat16* attB = (__hip_bfloat16*)(arena + Nn * 52 * 4); // 64*72
    float abv = g.ab[0];
    for (int i = tid; i < 64 * 72; i += 512) attB[i] = __float2bfloat16(0.f);
    for (int idx = tid; idx < Nn * Nn; idx += 512) {
      int i = idx / Nn, j = idx - i * Nn;
      float t = g.o1[b * RP + i] + g.o2[b * RP + j] + abv;
      t = t > 0.f ? t : 0.3f * t;  // leaky_relu 0.3
      attL[i * 52 + j] = (g.adj[(size_t)b * Nn * Nn + idx] > 0) ? t : -9.0e15f;
    }
    __syncthreads();
    if (tid < Nn) {
      float m = -3.0e38f;
      for (int j = 0; j < Nn; ++j) m = fmaxf(m, attL[tid * 52 + j]);
      float s = 0.f;
      for (int j = 0; j < Nn; ++j) {
        float p = expf(attL[tid * 52 + j] - m);
        attL[tid * 52 + j] = p;
        s += p;
      }
      float inv = 1.f / s;
      for (int j = 0; j < Nn; ++j) attL[tid * 52 + j] *= inv;
    }
    __syncthreads();
    for (int idx = tid; idx < Nn * Nn; idx += 512) {
      int i = idx / Nn, j = idx - i * Nn;
      attB[i * 72 + j] = __float2bfloat16(attL[i * 52 + j]);
    }
    __syncthreads();
    int strip = wave & 3;     // row strip (same role as R8's w)
    int half = wave >> 2;     // column half (384 cols each)
    bf16x8 a0 = *(const bf16x8*)&attB[(strip * 16 + lr) * 72 + lq * 8];
    bf16x8 a1 = *(const bf16x8*)&attB[(strip * 16 + lr) * 72 + 32 + lq * 8];
#pragma unroll
    for (int s = 0; s < 24; ++s) {
      int gc = half * 384 + s * 16 + lr;
      const __hip_bfloat16* Bp = g.WhT + ((size_t)b * Hd + gc) * RP + lq * 8;
      f32x4 acc = {};
      acc = MFMA(a0, *(const bf16x8*)Bp, acc);
      acc = MFMA(a1, *(const bf16x8*)(Bp + 32), acc);
#pragma unroll
      for (int r = 0; r < 4; ++r) {
        float v = acc[r];
        v = v > 0.f ? v : expf(v) - 1.f;  // elu
        size_t off = ((size_t)b * RP + strip * 16 + lq * 4 + r) * Hd + gc;
        if (POST == 2) {
          v += g.xres[off];
          g.hf[off] = v;
        }
        g.hb[off] = __float2bfloat16(v);
      }
    }
  } else if (POST == 3) {
    // pool softmax + weighted sum + final linear for dialogue b.
    float* sc = (float*)arena;
    float* ds = (float*)(arena + 256);
    if (tid < 64) {
      int j = tid;
      float e = (j < Nn) ? g.o1[b * RP + j] : -3.0e38f;
      float m = e;
#pragma unroll
      for (int off = 32; off; off >>= 1) m = fmaxf(m, __shfl_xor(m, off));
      float p = (j < Nn) ? expf(e - m) : 0.f;
      float s = p;
#pragma unroll
      for (int off = 32; off; off >>= 1) s += __shfl_xor(s, off);
      if (j < Nn) sc[j] = p / s;
    }
    __syncthreads();
    for (int h = tid; h < Hd; h += 512) {
      float a = 0.f;
#pragma unroll 10
      for (int j = 0; j < Nn; ++j)
        a += sc[j] * g.h2[((size_t)b * RP + j) * Hd + h];
      ds[h] = a;
    }
    __syncthreads();
    for (int o = tid; o < On; o += 512) {
      float acc = g.bl[o];
      const uint4* wrp = (const uint4*)(g.Wlt + (size_t)o * Hd);
      for (int kk = 0; kk < Hd / 8; ++kk) {
        union { uint4 u; unsigned short s[8]; } w;
        w.u = wrp[kk];
#pragma unroll
        for (int t = 0; t < 8; ++t)
          acc += ds[kk * 8 + t] * __uint_as_float((unsigned)w.s[t] << 16);
      }
      g.out[(size_t)b * On + o] = acc;
    }
  }
}

// ===========================================================================
extern "C" void kernel_launch(void* const* d_in, const int* in_sizes, int n_in,
                              void* d_out, int out_size, void* d_ws, size_t ws_size,
                              hipStream_t stream) {
  const float* emb = (const float*)d_in[0];
  const int* ids = (const int*)d_in[1];
  const int* adj = (const int*)d_in[2];
  const float* W1 = (const float*)d_in[3];
  const float* b1 = (const float*)d_in[4];
  const float* a1 = (const float*)d_in[5];
  const float* ab1 = (const float*)d_in[6];
  const float* W2 = (const float*)d_in[7];
  const float* b2 = (const float*)d_in[8];
  const float* a2 = (const float*)d_in[9];
  const float* ab2 = (const float*)d_in[10];
  const float* Wa = (const float*)d_in[11];
  const float* ba = (const float*)d_in[12];
  const float* vv = (const float*)d_in[13];
  const float* Wl = (const float*)d_in[14];
  const float* bl = (const float*)d_in[15];
  float* out = (float*)d_out;

  char* p = (char*)d_ws;
  auto alloc = [&](size_t bytes) {
    char* r = p;
    p += (bytes + 255) & ~(size_t)255;
    return r;
  };
  __hip_bfloat16* Wt1 = (__hip_bfloat16*)alloc((size_t)Hd * Hd * 2);
  __hip_bfloat16* Wt2 = (__hip_bfloat16*)alloc((size_t)Hd * Hd * 2);
  __hip_bfloat16* Wta = (__hip_bfloat16*)alloc((size_t)Hd * Hd * 2);
  __hip_bfloat16* Wlt = (__hip_bfloat16*)alloc((size_t)Hd * On * 2);
  float* aux = (float*)alloc((size_t)AUXW * 4);
  float* ssrc1 = aux;
  float* sdst1 = aux + Bn * RP;
  float* ssrc2 = aux + 2 * Bn * RP;
  float* sdst2 = aux + 3 * Bn * RP;
  float* sraw = aux + 4 * Bn * RP;
  int* tick = (int*)(aux + 5 * Bn * RP);  // 3*Bn ints, zeroed by prep
  __hip_bfloat16* xb = (__hip_bfloat16*)alloc((size_t)Bn * RP * Hd * 2);
  float* xres = (float*)alloc((size_t)Bn * RP * Hd * 4);
  __hip_bfloat16* WhT1 = (__hip_bfloat16*)alloc((size_t)Bn * Hd * RP * 2);
  __hip_bfloat16* WhT2 = (__hip_bfloat16*)alloc((size_t)Bn * Hd * RP * 2);
  __hip_bfloat16* h1b = (__hip_bfloat16*)alloc((size_t)Bn * RP * Hd * 2);
  __hip_bfloat16* h2b = (__hip_bfloat16*)alloc((size_t)Bn * RP * Hd * 2);
  float* h2f = (float*)alloc((size_t)Bn * RP * Hd * 4);

  PrepArgs pa;
  pa.src[0] = W1; pa.src[1] = W2; pa.src[2] = Wa; pa.src[3] = Wl;
  pa.dst[0] = Wt1; pa.dst[1] = Wt2; pa.dst[2] = Wta; pa.dst[3] = Wlt;
  pa.emb = emb; pa.ids = ids; pa.xres = xres; pa.xb = xb; pa.aux = aux;
  prep_kernel<<<6481, 256, 0, stream>>>(pa);

  dim3 ggrid(Bn, Hd / 64);  // 64 x 12, 512 threads

  GArgs g1 = {};
  g1.A = xb; g1.Bt = Wt1; g1.bias = b1; g1.avec = a1;
  g1.WhT = WhT1; g1.o1 = ssrc1; g1.o2 = sdst1;
  g1.adj = adj; g1.ab = ab1; g1.hb = h1b;
  g1.tick = tick;
  gfuse_kernel<0, 1><<<ggrid, 512, 0, stream>>>(g1);

  GArgs g2 = {};
  g2.A = h1b; g2.Bt = Wt2; g2.bias = b2; g2.avec = a2;
  g2.WhT = WhT2; g2.o1 = ssrc2; g2.o2 = sdst2;
  g2.adj = adj; g2.ab = ab2; g2.xres = xres; g2.hf = h2f; g2.hb = h2b;
  g2.tick = tick + Bn;
  gfuse_kernel<0, 2><<<ggrid, 512, 0, stream>>>(g2);

  GArgs g3 = {};
  g3.A = h2b; g3.Bt = Wta; g3.bias = ba; g3.avec = vv;
  g3.o1 = sraw;
  g3.h2 = h2f; g3.Wlt = Wlt; g3.bl = bl; g3.out = out;
  g3.tick = tick + 2 * Bn;
  gfuse_kernel<1, 3><<<ggrid, 512, 0, stream>>>(g3);
}

// Round 11
// 255.863 us; speedup vs baseline: 1.3617x; 1.3617x over previous
//
#include <hip/hip_runtime.h>
#include <hip/hip_bf16.h>
#include <math.h>

typedef __attribute__((ext_vector_type(8))) short bf16x8;
typedef __attribute__((ext_vector_type(4))) float f32x4;
typedef __attribute__((ext_vector_type(4))) unsigned short u16x4;

constexpr int Bn = 64;    // dialogues
constexpr int Ln = 512;   // utterances
constexpr int Hd = 768;   // hidden
constexpr int Nn = 50;    // nodes per dialogue
constexpr int On = 768;   // output dim
constexpr int RP = 64;    // padded rows per dialogue (M = Bn*RP = 4096)

__device__ __forceinline__ f32x4 MFMA(bf16x8 a, bf16x8 b, f32x4 c) {
  return __builtin_amdgcn_mfma_f32_16x16x32_bf16(a, b, c, 0, 0, 0);
}
__device__ __forceinline__ unsigned short f2bb(float v) {
  __hip_bfloat16 h = __float2bfloat16(v);
  return *(unsigned short*)&h;
}
// Async global->LDS, 16B per lane. LDS dest = wave-uniform base + lane*16.
__device__ __forceinline__ void gload16(const void* g, void* l) {
  __builtin_amdgcn_global_load_lds(
      (const __attribute__((address_space(1))) void*)g,
      (__attribute__((address_space(3))) void*)l, 16, 0, 0);
}

// ===========================================================================
// prep, one launch, job ranges by blockIdx.x:
//   [0,2304)      transpose+cvt W1,W2,Wa,Wl (f32 -> bf16^T)
//   [2304,6400)   gather+PE into padded xb (bf16) / xres (f32); pad rows = 0
//   [6400,6480)   zero the 5*Bn*RP aux accumulator region
struct PrepArgs {
  const float* src[4];
  __hip_bfloat16* dst[4];
  const float* emb;
  const int* ids;
  float* xres;
  __hip_bfloat16* xb;
  float* aux;
};

__global__ __launch_bounds__(256) void prep_kernel(PrepArgs a) {
  int bx = blockIdx.x;
  if (bx < 2304) {
    __shared__ float tile[32][33];
    int job = bx / 576, t = bx % 576;
    const float* W = a.src[job];
    __hip_bfloat16* Wt = a.dst[job];
    int tx = (t % 24) * 32, ty = (t / 24) * 32;
    int c = threadIdx.x & 31, r0 = threadIdx.x >> 5;
    for (int r = r0; r < 32; r += 8)
      tile[r][c] = W[(size_t)(tx + r) * Hd + ty + c];
    __syncthreads();
    for (int r = r0; r < 32; r += 8)
      Wt[(size_t)(ty + r) * Hd + tx + c] = __float2bfloat16(tile[c][r]);
  } else if (bx < 6400) {
    int bn = bx - 2304;          // b*RP + i
    int b = bn >> 6, i = bn & 63;
    __hip_bfloat16* xbo = a.xb + (size_t)bn * Hd;
    float* xro = a.xres + (size_t)bn * Hd;
    if (i < Nn) {
      int id = a.ids[b * Nn + i];
      const float* src = a.emb + ((size_t)b * Ln + id) * Hd;
      const float kLog = 9.210340371976184f / (float)Hd;  // ln(10000)/H
      for (int h = threadIdx.x; h < Hd; h += 256) {
        float freq = expf(-(float)(h & ~1) * kLog);
        float ang = (float)i * freq;
        float v = src[h] + ((h & 1) ? cosf(ang) : sinf(ang));
        xbo[h] = __float2bfloat16(v);
        xro[h] = v;
      }
    } else {
      for (int h = threadIdx.x; h < Hd; h += 256) {
        xbo[h] = __float2bfloat16(0.f);
        xro[h] = 0.f;
      }
    }
  } else {
    int idx = (bx - 6400) * 256 + threadIdx.x;
    if (idx < 5 * Bn * RP) a.aux[idx] = 0.f;
  }
}

// ===========================================================================
// Per-dialogue GEMM tile: C = A[b*64..+64, :] @ Wt^T + bias, 64x64 per block.
// grid = (Bn, 12), block = 512 (8 waves), wave owns 16x32 sub-tile (R8).
// R11 change: 3-buffer K-pipeline with COUNTED vmcnt (T4): loads for tile k
// issue at iter k-2, wait is `vmcnt(2)` (2 newest stay in flight) + raw
// s_barrier — never vmcnt(0) in the main loop. Safety: at iter i the barrier
// proves all waves finished iter i-1's reads before anyone stages buffer
// (i+2)%3; the <=2 in-flight loads target (i+1)%3 which nobody reads now.
// Fragments + MFMA order identical to R8 -> bit-identical numerics.
// EPI 0: write Wh^T + fused src/dst dots. EPI 1: tanh(C+bias).v into o1.
template <int EPI>
__global__ __launch_bounds__(512) void gemm_kernel(
    const __hip_bfloat16* __restrict__ A, const __hip_bfloat16* __restrict__ Bt,
    const float* __restrict__ bias, __hip_bfloat16* __restrict__ WhT,
    const float* __restrict__ avec, float* __restrict__ o1,
    float* __restrict__ o2) {
  __shared__ __hip_bfloat16 As[3][64][64];   // 3 x 8KB
  __shared__ __hip_bfloat16 Bs[3][64][64];   // 3 x 8KB  (48KB total)
  int tid = threadIdx.x;
  int wave = tid >> 6, lane = tid & 63;
  int lr = lane & 15, lq = lane >> 4;
  int wr = wave >> 1, wc = wave & 1;
  int b = blockIdx.x, col0 = blockIdx.y * 64;
  int row0 = b * RP;

  // staging: per wave 1 gload16 for A and 1 for B per K-tile (8 rows x 128B).
  // lane l covers row (wave*8 + (l>>3)), physical chunk (l&7); source
  // pre-swizzled (both-sides XOR rule, proven R5-R8).
  int srow = wave * 8 + (lane >> 3);
  int swz = ((lane & 7) ^ (lane >> 3)) * 8;
  const __hip_bfloat16* Ap = A + (size_t)(row0 + srow) * Hd + swz;
  const __hip_bfloat16* Bp = Bt + (size_t)(col0 + srow) * Hd + swz;
  char* AsB = (char*)As;
  char* BsB = (char*)Bs;
  int ldsw = wave * 1024;  // wave-uniform dest base within a buffer

  auto stage = [&](int buf, int kt) {
    gload16(Ap + kt, AsB + buf * 8192 + ldsw);
    gload16(Bp + kt, BsB + buf * 8192 + ldsw);
  };

  f32x4 acc[2] = {};
  stage(0, 0);
  stage(1, 64);            // 4 loads in flight per wave
  int arow = wr * 16 + lr;
  int s7 = lr & 7;               // == arow&7 == (wc*32+ct*16+lr)&7
  int c0 = (lq ^ s7) * 16;
  int c1 = ((4 + lq) ^ s7) * 16;

#pragma unroll
  for (int i = 0; i < 11; ++i) {
    // drain all but the 2 newest loads -> buffer i%3 complete (FIFO drain,
    // m135 semantics); in-flight pair targets (i+1)%3 (untouched this iter).
    asm volatile("s_waitcnt vmcnt(2)" ::: "memory");
    __builtin_amdgcn_sched_barrier(0);
    __builtin_amdgcn_s_barrier();   // all waves: buf i%3 ready, i-1 reads done
    if (i < 10) stage((i + 2) % 3, (i + 2) * 64);
    const char* Ab = AsB + (i % 3) * 8192 + arow * 128;
    bf16x8 af0 = *(const bf16x8*)(Ab + c0);
    bf16x8 af1 = *(const bf16x8*)(Ab + c1);
#pragma unroll
    for (int ct = 0; ct < 2; ++ct) {
      const char* Bb = BsB + (i % 3) * 8192 + (wc * 32 + ct * 16 + lr) * 128;
      acc[ct] = MFMA(af0, *(const bf16x8*)(Bb + c0), acc[ct]);
      acc[ct] = MFMA(af1, *(const bf16x8*)(Bb + c1), acc[ct]);
    }
  }
  {  // final iter i=11: only its own 2 loads remain -> full drain required
    asm volatile("s_waitcnt vmcnt(0)" ::: "memory");
    __builtin_amdgcn_sched_barrier(0);
    __builtin_amdgcn_s_barrier();
    const char* Ab = AsB + (11 % 3) * 8192 + arow * 128;
    bf16x8 af0 = *(const bf16x8*)(Ab + c0);
    bf16x8 af1 = *(const bf16x8*)(Ab + c1);
#pragma unroll
    for (int ct = 0; ct < 2; ++ct) {
      const char* Bb = BsB + (11 % 3) * 8192 + (wc * 32 + ct * 16 + lr) * 128;
      acc[ct] = MFMA(af0, *(const bf16x8*)(Bb + c0), acc[ct]);
      acc[ct] = MFMA(af1, *(const bf16x8*)(Bb + c1), acc[ct]);
    }
  }

  int lrow0 = wr * 16 + lq * 4;  // local row base (0..60, mult of 4)
  if (EPI == 0) {
    float ps[4] = {}, pd[4] = {};
#pragma unroll
    for (int ct = 0; ct < 2; ++ct) {
      int gc = col0 + wc * 32 + ct * 16 + lr;
      float bv = bias[gc];
      float a_s = avec[gc], a_d = avec[Hd + gc];
      u16x4 pk;
#pragma unroll
      for (int r = 0; r < 4; ++r) {
        float v = acc[ct][r] + bv;
        pk[r] = f2bb(v);
        ps[r] += v * a_s;
        pd[r] += v * a_d;
      }
      *(u16x4*)(WhT + ((size_t)b * Hd + gc) * RP + lrow0) = pk;
    }
#pragma unroll
    for (int off = 8; off; off >>= 1)
#pragma unroll
      for (int r = 0; r < 4; ++r) {
        ps[r] += __shfl_xor(ps[r], off);
        pd[r] += __shfl_xor(pd[r], off);
      }
    if (lr == 0)
#pragma unroll
      for (int r = 0; r < 4; ++r) {
        int row = lrow0 + r;
        if (row < Nn) {
          atomicAdd(&o1[b * RP + row], ps[r]);
          atomicAdd(&o2[b * RP + row], pd[r]);
        }
      }
  } else {
    float pr[4] = {};
#pragma unroll
    for (int ct = 0; ct < 2; ++ct) {
      int gc = col0 + wc * 32 + ct * 16 + lr;
      float bv = bias[gc];
      float vv_ = avec[gc];
#pragma unroll
      for (int r = 0; r < 4; ++r) pr[r] += tanhf(acc[ct][r] + bv) * vv_;
    }
#pragma unroll
    for (int off = 8; off; off >>= 1)
#pragma unroll
      for (int r = 0; r < 4; ++r) pr[r] += __shfl_xor(pr[r], off);
    if (lr == 0)
#pragma unroll
      for (int r = 0; r < 4; ++r) {
        int row = lrow0 + r;
        if (row < Nn) atomicAdd(&o1[b * RP + row], pr[r]);
      }
  }
}

// ===========================================================================
// MFMA attention apply: grid = (Bn*12), block 256 (4 waves), 64 cols/block.
// att = softmax(mask(adj, leaky_relu(ssrc_i+sdst_j+ab))) built in LDS (f32),
// converted to zero-padded bf16 A-operand; B = WhT (global).
// h[row, gc] = elu(sum_j att[row][j] WhT[gc][j]) (+xres, +hf for LAYER 2).
template <int LAYER>
__global__ __launch_bounds__(256) void attf_kernel(
    const float* __restrict__ ssrc, const float* __restrict__ sdst,
    const int* __restrict__ adj, const float* __restrict__ ab,
    const __hip_bfloat16* __restrict__ WhT, const float* __restrict__ xres,
    float* __restrict__ hf, __hip_bfloat16* __restrict__ hb) {
  int b = blockIdx.x / 12, cg = blockIdx.x % 12;
  __shared__ float attL[Nn * 52];
  __shared__ __hip_bfloat16 attB[64 * 72];
  int tid = threadIdx.x;
  float abv = ab[0];
  for (int i = tid; i < 64 * 72; i += 256) attB[i] = __float2bfloat16(0.f);
  for (int idx = tid; idx < Nn * Nn; idx += 256) {
    int i = idx / Nn, j = idx - i * Nn;
    float t = ssrc[b * RP + i] + sdst[b * RP + j] + abv;
    t = t > 0.f ? t : 0.3f * t;  // leaky_relu 0.3
    attL[i * 52 + j] = (adj[(size_t)b * Nn * Nn + idx] > 0) ? t : -9.0e15f;
  }
  __syncthreads();
  if (tid < Nn) {
    float m = -3.0e38f;
    for (int j = 0; j < Nn; ++j) m = fmaxf(m, attL[tid * 52 + j]);
    float s = 0.f;
    for (int j = 0; j < Nn; ++j) {
      float p = expf(attL[tid * 52 + j] - m);
      attL[tid * 52 + j] = p;
      s += p;
    }
    float inv = 1.f / s;
    for (int j = 0; j < Nn; ++j) attL[tid * 52 + j] *= inv;
  }
  __syncthreads();
  for (int idx = tid; idx < Nn * Nn; idx += 256) {
    int i = idx / Nn, j = idx - i * Nn;
    attB[i * 72 + j] = __float2bfloat16(attL[i * 52 + j]);
  }
  __syncthreads();

  int w = tid >> 6, lane = tid & 63, lr = lane & 15, lq = lane >> 4;
  bf16x8 a0 = *(const bf16x8*)&attB[(w * 16 + lr) * 72 + lq * 8];
  bf16x8 a1 = *(const bf16x8*)&attB[(w * 16 + lr) * 72 + 32 + lq * 8];
#pragma unroll
  for (int s = 0; s < 4; ++s) {
    int gc = cg * 64 + s * 16 + lr;
    const __hip_bfloat16* Bp = WhT + ((size_t)b * Hd + gc) * RP + lq * 8;
    f32x4 acc = {};
    acc = MFMA(a0, *(const bf16x8*)Bp, acc);
    acc = MFMA(a1, *(const bf16x8*)(Bp + 32), acc);
#pragma unroll
    for (int r = 0; r < 4; ++r) {
      float v = acc[r];
      v = v > 0.f ? v : expf(v) - 1.f;  // elu
      size_t off = ((size_t)b * RP + w * 16 + lq * 4 + r) * Hd + gc;
      if (LAYER == 2) {
        v += xres[off];
        hf[off] = v;
      }
      hb[off] = __float2bfloat16(v);
    }
  }
}

// ===========================================================================
// Pool softmax + weighted sum + final linear. grid = Bn*3: 3 blocks per
// dialogue, each computing softmax+ds redundantly (bit-identical) and one
// 256-out slice of the final linear.
__global__ __launch_bounds__(256) void poolfinal_kernel(
    const float* __restrict__ sraw, const float* __restrict__ h2,
    const __hip_bfloat16* __restrict__ Wlt, const float* __restrict__ bl,
    float* __restrict__ out) {
  int b = blockIdx.x / 3, q = blockIdx.x % 3;
  __shared__ float sc[Nn];
  __shared__ float ds[Hd];
  if (threadIdx.x < 64) {
    int j = threadIdx.x;
    float e = (j < Nn) ? sraw[b * RP + j] : -3.0e38f;
    float m = e;
#pragma unroll
    for (int off = 32; off; off >>= 1) m = fmaxf(m, __shfl_xor(m, off));
    float p = (j < Nn) ? expf(e - m) : 0.f;
    float s = p;
#pragma unroll
    for (int off = 32; off; off >>= 1) s += __shfl_xor(s, off);
    if (j < Nn) sc[j] = p / s;
  }
  __syncthreads();
  for (int h = threadIdx.x; h < Hd; h += 256) {
    float a = 0.f;
#pragma unroll 10
    for (int j = 0; j < Nn; ++j) a += sc[j] * h2[((size_t)b * RP + j) * Hd + h];
    ds[h] = a;
  }
  __syncthreads();
  {
    int o = q * 256 + threadIdx.x;
    float acc = bl[o];
    const uint4* wr = (const uint4*)(Wlt + (size_t)o * Hd);
    for (int kk = 0; kk < Hd / 8; ++kk) {
      union { uint4 u; unsigned short s[8]; } w;
      w.u = wr[kk];
#pragma unroll
      for (int t = 0; t < 8; ++t)
        acc += ds[kk * 8 + t] * __uint_as_float((unsigned)w.s[t] << 16);
    }
    out[(size_t)b * On + o] = acc;
  }
}

// ===========================================================================
extern "C" void kernel_launch(void* const* d_in, const int* in_sizes, int n_in,
                              void* d_out, int out_size, void* d_ws, size_t ws_size,
                              hipStream_t stream) {
  const float* emb = (const float*)d_in[0];
  const int* ids = (const int*)d_in[1];
  const int* adj = (const int*)d_in[2];
  const float* W1 = (const float*)d_in[3];
  const float* b1 = (const float*)d_in[4];
  const float* a1 = (const float*)d_in[5];
  const float* ab1 = (const float*)d_in[6];
  const float* W2 = (const float*)d_in[7];
  const float* b2 = (const float*)d_in[8];
  const float* a2 = (const float*)d_in[9];
  const float* ab2 = (const float*)d_in[10];
  const float* Wa = (const float*)d_in[11];
  const float* ba = (const float*)d_in[12];
  const float* vv = (const float*)d_in[13];
  const float* Wl = (const float*)d_in[14];
  const float* bl = (const float*)d_in[15];
  float* out = (float*)d_out;

  char* p = (char*)d_ws;
  auto alloc = [&](size_t bytes) {
    char* r = p;
    p += (bytes + 255) & ~(size_t)255;
    return r;
  };
  __hip_bfloat16* Wt1 = (__hip_bfloat16*)alloc((size_t)Hd * Hd * 2);
  __hip_bfloat16* Wt2 = (__hip_bfloat16*)alloc((size_t)Hd * Hd * 2);
  __hip_bfloat16* Wta = (__hip_bfloat16*)alloc((size_t)Hd * Hd * 2);
  __hip_bfloat16* Wlt = (__hip_bfloat16*)alloc((size_t)Hd * On * 2);
  float* aux = (float*)alloc((size_t)5 * Bn * RP * 4);
  float* ssrc1 = aux;
  float* sdst1 = aux + Bn * RP;
  float* ssrc2 = aux + 2 * Bn * RP;
  float* sdst2 = aux + 3 * Bn * RP;
  float* sraw = aux + 4 * Bn * RP;
  __hip_bfloat16* xb = (__hip_bfloat16*)alloc((size_t)Bn * RP * Hd * 2);
  float* xres = (float*)alloc((size_t)Bn * RP * Hd * 4);
  __hip_bfloat16* WhT1 = (__hip_bfloat16*)alloc((size_t)Bn * Hd * RP * 2);
  __hip_bfloat16* WhT2 = (__hip_bfloat16*)alloc((size_t)Bn * Hd * RP * 2);
  __hip_bfloat16* h1b = (__hip_bfloat16*)alloc((size_t)Bn * RP * Hd * 2);
  __hip_bfloat16* h2b = (__hip_bfloat16*)alloc((size_t)Bn * RP * Hd * 2);
  float* h2f = (float*)alloc((size_t)Bn * RP * Hd * 4);

  PrepArgs pa;
  pa.src[0] = W1; pa.src[1] = W2; pa.src[2] = Wa; pa.src[3] = Wl;
  pa.dst[0] = Wt1; pa.dst[1] = Wt2; pa.dst[2] = Wta; pa.dst[3] = Wlt;
  pa.emb = emb; pa.ids = ids; pa.xres = xres; pa.xb = xb; pa.aux = aux;
  prep_kernel<<<6480, 256, 0, stream>>>(pa);

  dim3 ggrid(Bn, Hd / 64);   // 64 x 12, 512 threads (8 waves)
  dim3 agrid(Bn * 12);       // 768 blocks, 64 cols each
  dim3 pgrid(Bn * 3);        // 192 blocks, 256 outs each

  // --- GAT layer 1 ---
  gemm_kernel<0><<<ggrid, 512, 0, stream>>>(xb, Wt1, b1, WhT1, a1, ssrc1, sdst1);
  attf_kernel<1><<<agrid, 256, 0, stream>>>(ssrc1, sdst1, adj, ab1, WhT1,
                                            nullptr, nullptr, h1b);
  // --- GAT layer 2 (+ residual) ---
  gemm_kernel<0><<<ggrid, 512, 0, stream>>>(h1b, Wt2, b2, WhT2, a2, ssrc2, sdst2);
  attf_kernel<2><<<agrid, 256, 0, stream>>>(ssrc2, sdst2, adj, ab2, WhT2, xres,
                                            h2f, h2b);
  // --- pooling scores: sraw = tanh(h2 @ Wa + ba) . v ---
  gemm_kernel<1><<<ggrid, 512, 0, stream>>>(h2b, Wta, ba, nullptr, vv, sraw,
                                            nullptr);
  // --- pool + final linear ---
  poolfinal_kernel<<<pgrid, 256, 0, stream>>>(sraw, h2f, Wlt, bl, out);
}